// Round 1
// baseline (158.074 us; speedup 1.0000x reference)
//
#include <hip/hip_runtime.h>
#include <math.h>

// Net_90434831385322: z = A + span*sigmoid(relu((x-A)/span @ W1 + b1) @ W2 + b2)
// BATCH=4194304, OBS=4, HID=64, ACT=4, all fp32.
//
// R4: FORCE v_pk_fma_f32 via inline asm. R3's float2 VFMA was scalarized by
//     the compiler (evidence: VALUBusy 65% matches the scalar instr-count
//     model ~55-65%, not the packed model ~33%; VGPR_Count=56 < the 64 regs
//     needed just to keep X+Ac resident as pairs). Single-instruction asm
//     with pure register dataflow stays schedulable by LLVM and pins the
//     v2f values into even-aligned VGPR pairs.
//     Weights remain DUPLICATED in LDS ({w,w} pairs, broadcast ds_read_b128,
//     bank-conflict-free) so packed operands need no per-j replication movs.

#define BATCH   4194304
#define HID     64
#define ROWS    8                         // 4 packed pairs per thread
#define TPB     256
#define NBLK    (BATCH / (TPB * ROWS))    // 2048 blocks

// ws layout (floats): per j (20-float block, 80B, 16B-aligned):
//   [j*20 + 0.. 7]  w1 duplicated: {w1x,w1x,w1y,w1y,w1z,w1z,w1w,w1w}  (input-scale folded)
//   [j*20 + 8..15]  w2 duplicated: {w2x,w2x,w2y,w2y,w2z,w2z,w2w,w2w}
//   [j*20 +16..17]  {b1'j, b1'j}
//   [j*20 +18..19]  pad
//   [1280..1283]    b2[0..3]
#define WS_FLOATS 1284

typedef float v2f __attribute__((ext_vector_type(2)));
typedef float v4f __attribute__((ext_vector_type(4)));

// Packed fp32 FMA: d = a*b + c on both 32-bit halves. One VOP3P instruction.
// No volatile, no memory clobber -> LLVM may still CSE/schedule freely.
static __device__ __forceinline__ v2f pk_fma(v2f a, v2f b, v2f c) {
    v2f d;
    asm("v_pk_fma_f32 %0, %1, %2, %3" : "=v"(d) : "v"(a), "v"(b), "v"(c));
    return d;
}

// relu on a pair: no v_pk_max_f32 on CDNA -> 2x v_max_f32.
static __device__ __forceinline__ v2f vmax0(v2f t) {
    v2f r;
    r.x = fmaxf(t.x, 0.0f);
    r.y = fmaxf(t.y, 0.0f);
    return r;
}

__global__ __launch_bounds__(64)
void prep_kernel(const float* __restrict__ W1, const float* __restrict__ b1,
                 const float* __restrict__ W2, const float* __restrict__ b2,
                 float* __restrict__ ws) {
    const float A[4] = {0.001f, 0.02f, 0.05f, 0.001f};
    const float S[4] = {0.003f, 0.03f, 0.15f, 0.003f};  // span = B - A
    int j = threadIdx.x;  // 0..63
    if (j < HID) {
        float bb = b1[j];
        #pragma unroll
        for (int k = 0; k < 4; ++k) {
            float wv = W1[k * HID + j];
            float wd = wv / S[k];               // fold input scaling into W1
            bb -= (A[k] / S[k]) * wv;           // and into b1
            ws[j * 20 + 2 * k]     = wd;
            ws[j * 20 + 2 * k + 1] = wd;
        }
        #pragma unroll
        for (int i = 0; i < 4; ++i) {
            float wv = W2[j * 4 + i];
            ws[j * 20 + 8 + 2 * i]     = wv;
            ws[j * 20 + 8 + 2 * i + 1] = wv;
        }
        ws[j * 20 + 16] = bb;
        ws[j * 20 + 17] = bb;
        ws[j * 20 + 18] = 0.0f;
        ws[j * 20 + 19] = 0.0f;
    }
    if (j < 4) ws[1280 + j] = b2[j];
}

__global__ __launch_bounds__(TPB, 4)
void mlp_kernel(const float* __restrict__ x, const float* __restrict__ ws,
                float* __restrict__ out) {
    __shared__ __align__(16) float s[WS_FLOATS];
    for (int i = threadIdx.x; i < WS_FLOATS; i += TPB) s[i] = ws[i];
    __syncthreads();

    const long base = (long)blockIdx.x * (TPB * ROWS) + threadIdx.x;
    const v4f* __restrict__ x4   = (const v4f*)x;
    v4f* __restrict__       out4 = (v4f*)out;

    // 8 rows, coalesced dwordx4 loads.
    v4f xr[ROWS];
    #pragma unroll
    for (int r = 0; r < ROWS; ++r) xr[r] = x4[base + (long)r * TPB];

    // Pack rows (2p, 2p+1) element-wise into float2 pairs (one-time movs).
    v2f X[4][4];
    #pragma unroll
    for (int p = 0; p < 4; ++p)
        #pragma unroll
        for (int e = 0; e < 4; ++e) {
            v2f t = {xr[2 * p][e], xr[2 * p + 1][e]};
            X[p][e] = t;
        }

    // Acc: Ac[p][c] = {y_c(row 2p), y_c(row 2p+1)}, init b2[c].
    v2f Ac[4][4];
    #pragma unroll
    for (int p = 0; p < 4; ++p)
        #pragma unroll
        for (int c = 0; c < 4; ++c) {
            v2f t = {s[1280 + c], s[1280 + c]};
            Ac[p][c] = t;
        }

    const v4f* sw = (const v4f*)s;

    // Per j: 4x ds_read_b128 + 1x b64 (broadcast, conflict-free), then
    // 4 pairs x (8 pk_fma + 2 v_max) = 40 VALU for 8 rows of both layers.
    #pragma unroll 4
    for (int j = 0; j < HID; ++j) {
        const v4f q0 = sw[j * 5 + 0];            // w1x w1x w1y w1y
        const v4f q1 = sw[j * 5 + 1];            // w1z w1z w1w w1w
        const v4f q2 = sw[j * 5 + 2];            // w2x w2x w2y w2y
        const v4f q3 = sw[j * 5 + 3];            // w2z w2z w2w w2w
        const v2f bb = *(const v2f*)(s + j * 20 + 16);
        #pragma unroll
        for (int p = 0; p < 4; ++p) {
            v2f t = pk_fma(X[p][0], q0.xy, bb);
            t = pk_fma(X[p][1], q0.zw, t);
            t = pk_fma(X[p][2], q1.xy, t);
            t = pk_fma(X[p][3], q1.zw, t);
            t = vmax0(t);
            Ac[p][0] = pk_fma(t, q2.xy, Ac[p][0]);
            Ac[p][1] = pk_fma(t, q2.zw, Ac[p][1]);
            Ac[p][2] = pk_fma(t, q3.xy, Ac[p][2]);
            Ac[p][3] = pk_fma(t, q3.zw, Ac[p][3]);
        }
    }

    // z = A + span * sigmoid(y):  z_c = fma(span_c, 1/(1+exp(-y_c)), A_c)
    const float LA[4] = {0.001f, 0.02f, 0.05f, 0.001f};
    const float LS[4] = {0.003f, 0.03f, 0.15f, 0.003f};
    #pragma unroll
    for (int p = 0; p < 4; ++p) {
        v4f z0, z1;
        #pragma unroll
        for (int c = 0; c < 4; ++c) {
            z0[c] = fmaf(LS[c], 1.0f / (1.0f + __expf(-Ac[p][c].x)), LA[c]);
            z1[c] = fmaf(LS[c], 1.0f / (1.0f + __expf(-Ac[p][c].y)), LA[c]);
        }
        out4[base + (long)(2 * p) * TPB]     = z0;
        out4[base + (long)(2 * p + 1) * TPB] = z1;
    }
}

extern "C" void kernel_launch(void* const* d_in, const int* in_sizes, int n_in,
                              void* d_out, int out_size, void* d_ws, size_t ws_size,
                              hipStream_t stream) {
    const float* x  = (const float*)d_in[0];
    const float* W1 = (const float*)d_in[1];
    const float* b1 = (const float*)d_in[2];
    const float* W2 = (const float*)d_in[3];
    const float* b2 = (const float*)d_in[4];
    float* out = (float*)d_out;
    float* ws  = (float*)d_ws;

    prep_kernel<<<1, 64, 0, stream>>>(W1, b1, W2, b2, ws);
    mlp_kernel<<<NBLK, TPB, 0, stream>>>(x, ws, out);
}